// Round 10
// baseline (1189.757 us; speedup 1.0000x reference)
//
#include <hip/hip_runtime.h>
#include <hip/hip_bf16.h>
#include <cstdint>
#include <cstddef>

static constexpr int NN = 100000;   // nodes
static constexpr int NE = 1600000;  // edges
static constexpr int NB = 391;      // buckets of 256 rows
static constexpr int GB = 250;      // blocks in hist/bucket passes (250*6400 == NE)
static constexpr int CHUNK = NE / GB;             // 6400 (int4-aligned chunks)
static constexpr int MCNT = NB * GB;              // 97750

static __device__ __forceinline__ unsigned short f2bf(float f) {
  unsigned u = __float_as_uint(f);
  unsigned r = (u + 0x7fffu + ((u >> 16) & 1u)) >> 16;  // RNE
  return (unsigned short)r;
}

// ---------------- pass A: per-(bucket,block) histogram (int4 reads) ----------------

__global__ __launch_bounds__(256) void k_hist(const int* __restrict__ row,
                                              int* __restrict__ counts) {
  __shared__ int hist[NB];
  for (int k = threadIdx.x; k < NB; k += 256) hist[k] = 0;
  __syncthreads();
  int g = blockIdx.x;
  int start = g * CHUNK;
  for (int gi = threadIdx.x; gi < CHUNK / 4; gi += 256) {
    int4 r4 = *reinterpret_cast<const int4*>(row + start + gi * 4);
    atomicAdd(&hist[r4.x >> 8], 1);
    atomicAdd(&hist[r4.y >> 8], 1);
    atomicAdd(&hist[r4.z >> 8], 1);
    atomicAdd(&hist[r4.w >> 8], 1);
  }
  __syncthreads();
  for (int k = threadIdx.x; k < NB; k += 256) counts[k * GB + g] = hist[k];
}

// ---------------- generic 2-level exclusive scan ----------------

__global__ __launch_bounds__(256) void k_bsumG(const int* __restrict__ a,
                                               int* __restrict__ bsum, int M) {
  __shared__ int s[256];
  int i = blockIdx.x * 256 + threadIdx.x;
  s[threadIdx.x] = (i < M) ? a[i] : 0;
  __syncthreads();
  for (int off = 128; off > 0; off >>= 1) {
    if (threadIdx.x < off) s[threadIdx.x] += s[threadIdx.x + off];
    __syncthreads();
  }
  if (threadIdx.x == 0) bsum[blockIdx.x] = s[0];
}

__global__ __launch_bounds__(256) void k_scan_bsum(int* __restrict__ bsum, int nb) {
  __shared__ int s[256];
  __shared__ int carry;
  if (threadIdx.x == 0) carry = 0;
  __syncthreads();
  for (int base = 0; base < nb; base += 256) {
    int i = base + threadIdx.x;
    int v = (i < nb) ? bsum[i] : 0;
    s[threadIdx.x] = v;
    __syncthreads();
    for (int off = 1; off < 256; off <<= 1) {
      int t = (threadIdx.x >= off) ? s[threadIdx.x - off] : 0;
      __syncthreads();
      s[threadIdx.x] += t;
      __syncthreads();
    }
    int exc = carry + s[threadIdx.x] - v;
    if (i < nb) bsum[i] = exc;
    int tile_total = s[255];
    __syncthreads();
    if (threadIdx.x == 0) carry += tile_total;
    __syncthreads();
  }
}

__global__ __launch_bounds__(256) void k_scan_finalG(int* __restrict__ a,
                                                     const int* __restrict__ bsum,
                                                     int M) {
  __shared__ int s[256];
  int i = blockIdx.x * 256 + threadIdx.x;
  int v = (i < M) ? a[i] : 0;
  s[threadIdx.x] = v;
  __syncthreads();
  for (int off = 1; off < 256; off <<= 1) {
    int t = (threadIdx.x >= off) ? s[threadIdx.x - off] : 0;
    __syncthreads();
    s[threadIdx.x] += t;
    __syncthreads();
  }
  if (i < M) a[i] = bsum[blockIdx.x] + s[threadIdx.x] - v;
}

// ---------------- pass B: bucket-grouped packed edges (int4 reads) ----------------

__global__ __launch_bounds__(256) void k_bucket(const int* __restrict__ row,
                                                const int* __restrict__ col,
                                                const int* __restrict__ counts,
                                                unsigned int* __restrict__ packed) {
  __shared__ int cur[NB];
  int g = blockIdx.x;
  for (int k = threadIdx.x; k < NB; k += 256) cur[k] = counts[k * GB + g];
  __syncthreads();
  int start = g * CHUNK;
  for (int gi = threadIdx.x; gi < CHUNK / 4; gi += 256) {
    int4 r4 = *reinterpret_cast<const int4*>(row + start + gi * 4);
    int4 c4 = *reinterpret_cast<const int4*>(col + start + gi * 4);
    int p0 = atomicAdd(&cur[r4.x >> 8], 1);
    int p1 = atomicAdd(&cur[r4.y >> 8], 1);
    int p2 = atomicAdd(&cur[r4.z >> 8], 1);
    int p3 = atomicAdd(&cur[r4.w >> 8], 1);
    packed[p0] = ((unsigned)(r4.x & 255) << 17) | (unsigned)c4.x;
    packed[p1] = ((unsigned)(r4.y & 255) << 17) | (unsigned)c4.y;
    packed[p2] = ((unsigned)(r4.z & 255) << 17) | (unsigned)c4.z;
    packed[p3] = ((unsigned)(r4.w & 255) << 17) | (unsigned)c4.w;
  }
}

// ---------------- pass C: per-bucket CSR finalize + fused x-cast ----------------

__global__ __launch_bounds__(256) void k_csr(const unsigned int* __restrict__ packed,
                                             const int* __restrict__ counts,
                                             int* __restrict__ rowptr,
                                             float* __restrict__ dis,
                                             int* __restrict__ csr_col,
                                             const float* __restrict__ x,
                                             unsigned short* __restrict__ xb,
                                             int N, int E) {
  __shared__ int rh[256];
  __shared__ int sc[256];
  __shared__ int cur[256];
  __shared__ float ldis[256];
  int b = blockIdx.x;
  int start = counts[b * GB];
  int end = (b + 1 < NB) ? counts[(b + 1) * GB] : E;

  rh[threadIdx.x] = 0;
  __syncthreads();
  for (int i = start + threadIdx.x; i < end; i += 256)
    atomicAdd(&rh[packed[i] >> 17], 1);
  __syncthreads();

  int v = rh[threadIdx.x];
  sc[threadIdx.x] = v;
  __syncthreads();
  for (int off = 1; off < 256; off <<= 1) {
    int t = (threadIdx.x >= off) ? sc[threadIdx.x - off] : 0;
    __syncthreads();
    sc[threadIdx.x] += t;
    __syncthreads();
  }
  int exc = sc[threadIdx.x] - v;

  float dv = 1.0f / sqrtf((float)v + 1e-12f);
  ldis[threadIdx.x] = dv;
  int gr = (b << 8) + threadIdx.x;
  if (gr < N) {
    rowptr[gr] = start + exc;
    dis[gr] = dv;
  }
  if (b == NB - 1 && threadIdx.x == 0) rowptr[N] = E;

  cur[threadIdx.x] = exc;
  __syncthreads();
  for (int i = start + threadIdx.x; i < end; i += 256) {
    unsigned p = packed[i];
    int lr = p >> 17;
    int c = (int)(p & 0x1FFFFu);
    int pos = atomicAdd(&cur[lr], 1);
    csr_col[start + pos] = c;
  }

  // fused cast: this bucket's rows of x -> bf16 * dis (coalesced float4 loop)
  int rows = min(256, N - (b << 8));
  if (rows > 0) {
    const float4* xs = reinterpret_cast<const float4*>(x + ((size_t)b << 8) * 32);
    ushort4* xd = reinterpret_cast<ushort4*>(xb + ((size_t)b << 8) * 32);
    for (int i = threadIdx.x; i < rows * 8; i += 256) {
      float ds = ldis[i >> 3];
      float4 vv = xs[i];
      xd[i] = make_ushort4(f2bf(vv.x * ds), f2bf(vv.y * ds),
                           f2bf(vv.z * ds), f2bf(vv.w * ds));
    }
  }
}

// ---------------- bf16 accumulate helper ----------------

template <int SQ>
static __device__ __forceinline__ void acc_bf(float* acc, const uint4* u) {
#pragma unroll
  for (int q = 0; q < SQ; ++q) {
    acc[8 * q + 0] += __uint_as_float(u[q].x << 16);
    acc[8 * q + 1] += __uint_as_float(u[q].x & 0xffff0000u);
    acc[8 * q + 2] += __uint_as_float(u[q].y << 16);
    acc[8 * q + 3] += __uint_as_float(u[q].y & 0xffff0000u);
    acc[8 * q + 4] += __uint_as_float(u[q].z << 16);
    acc[8 * q + 5] += __uint_as_float(u[q].z & 0xffff0000u);
    acc[8 * q + 6] += __uint_as_float(u[q].w << 16);
    acc[8 * q + 7] += __uint_as_float(u[q].w & 0xffff0000u);
  }
}

// ---------------- bf16 gather (4-deep): dst[r,:] = dis[r]*sum src[col,:] ----------------

template <int LPR, int SQ>
__global__ __launch_bounds__(256) void k_gather_bf(const uint4* __restrict__ src,
                                                   const int* __restrict__ rowptr,
                                                   const int* __restrict__ csr_col,
                                                   const float* __restrict__ dis,
                                                   float* __restrict__ dst, int N) {
  constexpr int RQ = LPR * SQ;
  constexpr int W = RQ * 8;
  int t = blockIdx.x * 256 + threadIdx.x;
  int r = t / LPR, g = t % LPR;
  if (r >= N) return;
  int j = rowptr[r], end = rowptr[r + 1];

  float acc[SQ * 8];
#pragma unroll
  for (int q = 0; q < SQ * 8; ++q) acc[q] = 0.f;

  for (; j + 4 <= end; j += 4) {
    int c0 = csr_col[j], c1 = csr_col[j + 1], c2 = csr_col[j + 2], c3 = csr_col[j + 3];
    const uint4* sp0 = src + (size_t)c0 * RQ + g * SQ;
    const uint4* sp1 = src + (size_t)c1 * RQ + g * SQ;
    const uint4* sp2 = src + (size_t)c2 * RQ + g * SQ;
    const uint4* sp3 = src + (size_t)c3 * RQ + g * SQ;
    uint4 u0[SQ], u1[SQ], u2[SQ], u3[SQ];
#pragma unroll
    for (int q = 0; q < SQ; ++q) u0[q] = sp0[q];
#pragma unroll
    for (int q = 0; q < SQ; ++q) u1[q] = sp1[q];
#pragma unroll
    for (int q = 0; q < SQ; ++q) u2[q] = sp2[q];
#pragma unroll
    for (int q = 0; q < SQ; ++q) u3[q] = sp3[q];
    acc_bf<SQ>(acc, u0);
    acc_bf<SQ>(acc, u1);
    acc_bf<SQ>(acc, u2);
    acc_bf<SQ>(acc, u3);
  }
  for (; j < end; ++j) {
    int c0 = csr_col[j];
    const uint4* sp0 = src + (size_t)c0 * RQ + g * SQ;
    uint4 u0[SQ];
#pragma unroll
    for (int q = 0; q < SQ; ++q) u0[q] = sp0[q];
    acc_bf<SQ>(acc, u0);
  }

  float ds = dis[r];
  float4* dp = reinterpret_cast<float4*>(dst + (size_t)r * W + g * (SQ * 8));
#pragma unroll
  for (int q = 0; q < SQ * 2; ++q)
    dp[q] = make_float4(ds * acc[4 * q + 0], ds * acc[4 * q + 1],
                        ds * acc[4 * q + 2], ds * acc[4 * q + 3]);
}

// ---------------- fused double GEMM, TM=2 rows/thread ----------------
// s2 = bf16(dis*(relu(g1@W1)@W2)), rows padded to 64 bf16.
// 128-thread blocks, 256 rows/block (grid 391): the 960 broadcast ds_read_b128
// per wave now serve TWO rows each — DS-pipe issue cost per row halves, and the
// wave becomes FMA-bound. f-blocked GEMM2 keeps live VGPRs ≈ h[96]+o[32]+w.

__global__ __launch_bounds__(128, 2) void k_gemm12(const float* __restrict__ g1,
                                                   const float* __restrict__ W1,
                                                   const float* __restrict__ W2,
                                                   const float* __restrict__ dis,
                                                   unsigned short* __restrict__ s2,
                                                   int N) {
  __shared__ float W1l[32 * 48];
  __shared__ float W2l[48 * 48];
  for (int i = threadIdx.x; i < 32 * 48; i += 128) W1l[i] = W1[i];
  for (int i = threadIdx.x; i < 48 * 48; i += 128) W2l[i] = W2[i];
  __syncthreads();

  int r0 = blockIdx.x * 256 + threadIdx.x;  // rows r0 and r0+128
  int r1 = r0 + 128;
  bool v0ok = (r0 < N), v1ok = (r1 < N);

  float h0[48], h1[48];
#pragma unroll
  for (int f = 0; f < 48; ++f) { h0[f] = 0.f; h1[f] = 0.f; }

  const float4* xp0 = reinterpret_cast<const float4*>(g1 + (size_t)r0 * 32);
  const float4* xp1 = reinterpret_cast<const float4*>(g1 + (size_t)r1 * 32);
#pragma unroll
  for (int k4 = 0; k4 < 8; ++k4) {
    float4 va = v0ok ? xp0[k4] : make_float4(0.f, 0.f, 0.f, 0.f);
    float4 vb = v1ok ? xp1[k4] : make_float4(0.f, 0.f, 0.f, 0.f);
    const float* w0 = &W1l[(4 * k4 + 0) * 48];
    const float* w1 = &W1l[(4 * k4 + 1) * 48];
    const float* w2 = &W1l[(4 * k4 + 2) * 48];
    const float* w3 = &W1l[(4 * k4 + 3) * 48];
#pragma unroll
    for (int f4 = 0; f4 < 12; ++f4) {
      float4 a = *reinterpret_cast<const float4*>(w0 + 4 * f4);
      float4 b = *reinterpret_cast<const float4*>(w1 + 4 * f4);
      float4 c = *reinterpret_cast<const float4*>(w2 + 4 * f4);
      float4 d = *reinterpret_cast<const float4*>(w3 + 4 * f4);
      h0[4 * f4 + 0] = fmaf(va.x, a.x, fmaf(va.y, b.x, fmaf(va.z, c.x, fmaf(va.w, d.x, h0[4 * f4 + 0]))));
      h0[4 * f4 + 1] = fmaf(va.x, a.y, fmaf(va.y, b.y, fmaf(va.z, c.y, fmaf(va.w, d.y, h0[4 * f4 + 1]))));
      h0[4 * f4 + 2] = fmaf(va.x, a.z, fmaf(va.y, b.z, fmaf(va.z, c.z, fmaf(va.w, d.z, h0[4 * f4 + 2]))));
      h0[4 * f4 + 3] = fmaf(va.x, a.w, fmaf(va.y, b.w, fmaf(va.z, c.w, fmaf(va.w, d.w, h0[4 * f4 + 3]))));
      h1[4 * f4 + 0] = fmaf(vb.x, a.x, fmaf(vb.y, b.x, fmaf(vb.z, c.x, fmaf(vb.w, d.x, h1[4 * f4 + 0]))));
      h1[4 * f4 + 1] = fmaf(vb.x, a.y, fmaf(vb.y, b.y, fmaf(vb.z, c.y, fmaf(vb.w, d.y, h1[4 * f4 + 1]))));
      h1[4 * f4 + 2] = fmaf(vb.x, a.z, fmaf(vb.y, b.z, fmaf(vb.z, c.z, fmaf(vb.w, d.z, h1[4 * f4 + 2]))));
      h1[4 * f4 + 3] = fmaf(vb.x, a.w, fmaf(vb.y, b.w, fmaf(vb.z, c.w, fmaf(vb.w, d.w, h1[4 * f4 + 3]))));
    }
  }
#pragma unroll
  for (int f = 0; f < 48; ++f) {
    h0[f] = fmaxf(h0[f], 0.f);
    h1[f] = fmaxf(h1[f], 0.f);
  }

  float ds0 = v0ok ? dis[r0] : 0.f;
  float ds1 = v1ok ? dis[r1] : 0.f;
  uint4* op0 = reinterpret_cast<uint4*>(s2 + (size_t)r0 * 64);
  uint4* op1 = reinterpret_cast<uint4*>(s2 + (size_t)r1 * 64);

#pragma unroll
  for (int fb = 0; fb < 3; ++fb) {  // 16 output features per block
    float o0[16], o1[16];
#pragma unroll
    for (int n = 0; n < 16; ++n) { o0[n] = 0.f; o1[n] = 0.f; }
#pragma unroll
    for (int k = 0; k < 48; ++k) {
      const float* wr = &W2l[k * 48 + fb * 16];
      float4 wa = *reinterpret_cast<const float4*>(wr);
      float4 wb = *reinterpret_cast<const float4*>(wr + 4);
      float4 wc = *reinterpret_cast<const float4*>(wr + 8);
      float4 wd = *reinterpret_cast<const float4*>(wr + 12);
      float a0 = h0[k], a1 = h1[k];
      o0[0] = fmaf(a0, wa.x, o0[0]);  o1[0] = fmaf(a1, wa.x, o1[0]);
      o0[1] = fmaf(a0, wa.y, o0[1]);  o1[1] = fmaf(a1, wa.y, o1[1]);
      o0[2] = fmaf(a0, wa.z, o0[2]);  o1[2] = fmaf(a1, wa.z, o1[2]);
      o0[3] = fmaf(a0, wa.w, o0[3]);  o1[3] = fmaf(a1, wa.w, o1[3]);
      o0[4] = fmaf(a0, wb.x, o0[4]);  o1[4] = fmaf(a1, wb.x, o1[4]);
      o0[5] = fmaf(a0, wb.y, o0[5]);  o1[5] = fmaf(a1, wb.y, o1[5]);
      o0[6] = fmaf(a0, wb.z, o0[6]);  o1[6] = fmaf(a1, wb.z, o1[6]);
      o0[7] = fmaf(a0, wb.w, o0[7]);  o1[7] = fmaf(a1, wb.w, o1[7]);
      o0[8] = fmaf(a0, wc.x, o0[8]);  o1[8] = fmaf(a1, wc.x, o1[8]);
      o0[9] = fmaf(a0, wc.y, o0[9]);  o1[9] = fmaf(a1, wc.y, o1[9]);
      o0[10] = fmaf(a0, wc.z, o0[10]); o1[10] = fmaf(a1, wc.z, o1[10]);
      o0[11] = fmaf(a0, wc.w, o0[11]); o1[11] = fmaf(a1, wc.w, o1[11]);
      o0[12] = fmaf(a0, wd.x, o0[12]); o1[12] = fmaf(a1, wd.x, o1[12]);
      o0[13] = fmaf(a0, wd.y, o0[13]); o1[13] = fmaf(a1, wd.y, o1[13]);
      o0[14] = fmaf(a0, wd.z, o0[14]); o1[14] = fmaf(a1, wd.z, o1[14]);
      o0[15] = fmaf(a0, wd.w, o0[15]); o1[15] = fmaf(a1, wd.w, o1[15]);
    }
    uint4 pk0[2], pk1[2];
    unsigned* pw0 = reinterpret_cast<unsigned*>(pk0);
    unsigned* pw1 = reinterpret_cast<unsigned*>(pk1);
#pragma unroll
    for (int i = 0; i < 8; ++i) {
      pw0[i] = (unsigned)f2bf(o0[2 * i] * ds0) |
               ((unsigned)f2bf(o0[2 * i + 1] * ds0) << 16);
      pw1[i] = (unsigned)f2bf(o1[2 * i] * ds1) |
               ((unsigned)f2bf(o1[2 * i + 1] * ds1) << 16);
    }
    if (v0ok) { op0[fb * 2] = pk0[0]; op0[fb * 2 + 1] = pk0[1]; }
    if (v1ok) { op1[fb * 2] = pk1[0]; op1[fb * 2 + 1] = pk1[1]; }
  }
  // pad features 48..63 with zeros
  uint4 z = make_uint4(0u, 0u, 0u, 0u);
  if (v0ok) { op0[6] = z; op0[7] = z; }
  if (v1ok) { op1[6] = z; op1[7] = z; }
}

// ---------------- fused layer-2 gather + layer-3 GEMM ----------------
// s3[r,:] = dis[r] * (relu(dis[r]*sum_j s2[col_j,:]) @ Wo)
// 8 lanes per row (padded 128B rows); shuffle-reduce over the 8-lane group.

__global__ __launch_bounds__(256) void k_gather_fc(const uint4* __restrict__ src,
                                                   const int* __restrict__ rowptr,
                                                   const int* __restrict__ csr_col,
                                                   const float* __restrict__ dis,
                                                   const float* __restrict__ Wo,
                                                   float* __restrict__ s3, int N) {
  __shared__ float Wol[64 * 8];
  for (int i = threadIdx.x; i < 512; i += 256) Wol[i] = (i < 384) ? Wo[i] : 0.f;
  __syncthreads();

  int t = blockIdx.x * 256 + threadIdx.x;
  int r = t >> 3, g = t & 7;
  if (r >= N) return;
  int j = rowptr[r], end = rowptr[r + 1];

  float acc[8];
#pragma unroll
  for (int q = 0; q < 8; ++q) acc[q] = 0.f;

  for (; j + 4 <= end; j += 4) {
    int c0 = csr_col[j], c1 = csr_col[j + 1], c2 = csr_col[j + 2], c3 = csr_col[j + 3];
    uint4 u0 = src[(size_t)c0 * 8 + g];
    uint4 u1 = src[(size_t)c1 * 8 + g];
    uint4 u2 = src[(size_t)c2 * 8 + g];
    uint4 u3 = src[(size_t)c3 * 8 + g];
    acc_bf<1>(acc, &u0);
    acc_bf<1>(acc, &u1);
    acc_bf<1>(acc, &u2);
    acc_bf<1>(acc, &u3);
  }
  for (; j < end; ++j) {
    uint4 u0 = src[(size_t)csr_col[j] * 8 + g];
    acc_bf<1>(acc, &u0);
  }

  float ds = dis[r];
  float v[8];
#pragma unroll
  for (int q = 0; q < 8; ++q) v[q] = fmaxf(ds * acc[q], 0.f);

  float p[8];
#pragma unroll
  for (int n = 0; n < 8; ++n) p[n] = 0.f;
  const int base = g * 8;
#pragma unroll
  for (int q = 0; q < 8; ++q) {
    float4 w0 = *reinterpret_cast<const float4*>(&Wol[(base + q) * 8]);
    float4 w1 = *reinterpret_cast<const float4*>(&Wol[(base + q) * 8 + 4]);
    p[0] = fmaf(v[q], w0.x, p[0]);
    p[1] = fmaf(v[q], w0.y, p[1]);
    p[2] = fmaf(v[q], w0.z, p[2]);
    p[3] = fmaf(v[q], w0.w, p[3]);
    p[4] = fmaf(v[q], w1.x, p[4]);
    p[5] = fmaf(v[q], w1.y, p[5]);
    p[6] = fmaf(v[q], w1.z, p[6]);
    p[7] = fmaf(v[q], w1.w, p[7]);
  }
#pragma unroll
  for (int m = 1; m < 8; m <<= 1) {
#pragma unroll
    for (int n = 0; n < 8; ++n) p[n] += __shfl_xor(p[n], m, 64);
  }
  if (g < 2) {
    float4 w = make_float4(ds * p[4 * g + 0], ds * p[4 * g + 1],
                           ds * p[4 * g + 2], ds * p[4 * g + 3]);
    *reinterpret_cast<float4*>(s3 + (size_t)r * 8 + 4 * g) = w;
  }
}

// ---------------- f32 gather (final 8-wide layer), 2-deep ----------------

template <int LPR, int FQ>
__global__ __launch_bounds__(256) void k_gather(const float* __restrict__ src,
                                                const int* __restrict__ rowptr,
                                                const int* __restrict__ csr_col,
                                                const float* __restrict__ dis,
                                                float* __restrict__ dst, int N) {
  constexpr int F = LPR * FQ * 4;
  int t = blockIdx.x * 256 + threadIdx.x;
  int r = t / LPR, g = t % LPR;
  if (r >= N) return;
  int j = rowptr[r], end = rowptr[r + 1];

  float acc[FQ * 4];
#pragma unroll
  for (int q = 0; q < FQ * 4; ++q) acc[q] = 0.f;

  for (; j + 2 <= end; j += 2) {
    int c0 = csr_col[j], c1 = csr_col[j + 1];
    const float4* sp0 =
        reinterpret_cast<const float4*>(src + (size_t)c0 * F + g * (FQ * 4));
    const float4* sp1 =
        reinterpret_cast<const float4*>(src + (size_t)c1 * F + g * (FQ * 4));
    float4 v0[FQ], v1[FQ];
#pragma unroll
    for (int q = 0; q < FQ; ++q) v0[q] = sp0[q];
#pragma unroll
    for (int q = 0; q < FQ; ++q) v1[q] = sp1[q];
#pragma unroll
    for (int q = 0; q < FQ; ++q) {
      acc[4 * q + 0] += v0[q].x + v1[q].x;
      acc[4 * q + 1] += v0[q].y + v1[q].y;
      acc[4 * q + 2] += v0[q].z + v1[q].z;
      acc[4 * q + 3] += v0[q].w + v1[q].w;
    }
  }
  if (j < end) {
    int c0 = csr_col[j];
    const float4* sp0 =
        reinterpret_cast<const float4*>(src + (size_t)c0 * F + g * (FQ * 4));
#pragma unroll
    for (int q = 0; q < FQ; ++q) {
      float4 v = sp0[q];
      acc[4 * q + 0] += v.x;
      acc[4 * q + 1] += v.y;
      acc[4 * q + 2] += v.z;
      acc[4 * q + 3] += v.w;
    }
  }

  float ds = dis[r];
  float4* dp = reinterpret_cast<float4*>(dst + (size_t)r * F + g * (FQ * 4));
#pragma unroll
  for (int q = 0; q < FQ; ++q)
    dp[q] = make_float4(ds * acc[4 * q + 0], ds * acc[4 * q + 1],
                        ds * acc[4 * q + 2], ds * acc[4 * q + 3]);
}

// ---------------- launch ----------------

extern "C" void kernel_launch(void* const* d_in, const int* in_sizes, int n_in,
                              void* d_out, int out_size, void* d_ws, size_t ws_size,
                              hipStream_t stream) {
  const float* x  = (const float*)d_in[0];
  const int*   ei = (const int*)d_in[1];
  const float* W1 = (const float*)d_in[2];
  const float* W2 = (const float*)d_in[3];
  const float* Wo = (const float*)d_in[4];
  float* out = (float*)d_out;

  const int N = NN, E = NE;
  const int* row = ei;
  const int* col = ei + E;
  const int scanG = (MCNT + 255) / 256;  // 382

  // workspace layout (word offsets; all 16B aligned)
  int*   counts  = (int*)d_ws;                   // 97752
  int*   bsum    = counts + 97752;               // 384
  int*   rowptr  = bsum + 384;                   // 100008
  float* dis     = (float*)(rowptr + 100008);    // 100000
  int*   csr_col = (int*)(dis + 100000);         // 1.6M
  float* A1      = (float*)(csr_col + NE);       // 3.2M words
  float* A2      = A1 + 3200000;                 // 4.0M words
  float* s3      = A2 + 4000000;                 // 800K words (N*8 f32)
  // aliases (lifetimes disjoint):
  unsigned int*   packed = (unsigned int*)A1;               // CSR build only
  unsigned short* s2     = (unsigned short*)A1;             // N*64 bf16 (padded)
  float*          g1     = A2;                              // N*32 f32
  unsigned short* xb     = (unsigned short*)(A2 + 3200000); // N*32 bf16

  // ---- CSR build (+fused cast) ----
  k_hist<<<GB, 256, 0, stream>>>(row, counts);
  k_bsumG<<<scanG, 256, 0, stream>>>(counts, bsum, MCNT);
  k_scan_bsum<<<1, 256, 0, stream>>>(bsum, scanG);
  k_scan_finalG<<<scanG, 256, 0, stream>>>(counts, bsum, MCNT);
  k_bucket<<<GB, 256, 0, stream>>>(row, col, counts, packed);
  k_csr<<<NB, 256, 0, stream>>>(packed, counts, rowptr, dis, csr_col, x, xb, N, E);

  // ---- layer 1 (reassociated): g1 = dis⊙(Ā@(dis⊙x)) ----
  k_gather_bf<4, 1><<<(N * 4 + 255) / 256, 256, 0, stream>>>(
      (const uint4*)xb, rowptr, csr_col, dis, g1, N);

  // ---- fused GEMM1+GEMM2 (TM=2): s2 = bf16(dis * (relu(g1@W1)@W2)), padded 64 ----
  k_gemm12<<<(N + 255) / 256, 128, 0, stream>>>(g1, W1, W2, dis, s2, N);

  // ---- fused layer-2 gather + layer-3 GEMM: s3 = dis*(relu(dis*(Ā@s2))@Wo) ----
  k_gather_fc<<<(N * 8 + 255) / 256, 256, 0, stream>>>(
      (const uint4*)s2, rowptr, csr_col, dis, Wo, s3, N);

  // ---- final gather: out = dis⊙(Ā@s3) ----
  k_gather<2, 1><<<(N * 2 + 255) / 256, 256, 0, stream>>>(s3, rowptr, csr_col,
                                                          dis, out, N);
}

// Round 11
// 184.855 us; speedup vs baseline: 6.4362x; 6.4362x over previous
//
#include <hip/hip_runtime.h>
#include <hip/hip_bf16.h>
#include <cstdint>
#include <cstddef>

static constexpr int NN = 100000;   // nodes
static constexpr int NE = 1600000;  // edges
static constexpr int NB = 391;      // buckets of 256 rows
static constexpr int GB = 250;      // blocks in hist/bucket passes (250*6400 == NE)
static constexpr int CHUNK = NE / GB;             // 6400 (int4-aligned chunks)
static constexpr int MCNT = NB * GB;              // 97750

static __device__ __forceinline__ unsigned short f2bf(float f) {
  unsigned u = __float_as_uint(f);
  unsigned r = (u + 0x7fffu + ((u >> 16) & 1u)) >> 16;  // RNE
  return (unsigned short)r;
}

// ---------------- pass A: per-(bucket,block) histogram (int4 reads) ----------------

__global__ __launch_bounds__(256) void k_hist(const int* __restrict__ row,
                                              int* __restrict__ counts) {
  __shared__ int hist[NB];
  for (int k = threadIdx.x; k < NB; k += 256) hist[k] = 0;
  __syncthreads();
  int g = blockIdx.x;
  int start = g * CHUNK;
  for (int gi = threadIdx.x; gi < CHUNK / 4; gi += 256) {
    int4 r4 = *reinterpret_cast<const int4*>(row + start + gi * 4);
    atomicAdd(&hist[r4.x >> 8], 1);
    atomicAdd(&hist[r4.y >> 8], 1);
    atomicAdd(&hist[r4.z >> 8], 1);
    atomicAdd(&hist[r4.w >> 8], 1);
  }
  __syncthreads();
  for (int k = threadIdx.x; k < NB; k += 256) counts[k * GB + g] = hist[k];
}

// ---------------- generic 2-level exclusive scan ----------------

__global__ __launch_bounds__(256) void k_bsumG(const int* __restrict__ a,
                                               int* __restrict__ bsum, int M) {
  __shared__ int s[256];
  int i = blockIdx.x * 256 + threadIdx.x;
  s[threadIdx.x] = (i < M) ? a[i] : 0;
  __syncthreads();
  for (int off = 128; off > 0; off >>= 1) {
    if (threadIdx.x < off) s[threadIdx.x] += s[threadIdx.x + off];
    __syncthreads();
  }
  if (threadIdx.x == 0) bsum[blockIdx.x] = s[0];
}

__global__ __launch_bounds__(256) void k_scan_bsum(int* __restrict__ bsum, int nb) {
  __shared__ int s[256];
  __shared__ int carry;
  if (threadIdx.x == 0) carry = 0;
  __syncthreads();
  for (int base = 0; base < nb; base += 256) {
    int i = base + threadIdx.x;
    int v = (i < nb) ? bsum[i] : 0;
    s[threadIdx.x] = v;
    __syncthreads();
    for (int off = 1; off < 256; off <<= 1) {
      int t = (threadIdx.x >= off) ? s[threadIdx.x - off] : 0;
      __syncthreads();
      s[threadIdx.x] += t;
      __syncthreads();
    }
    int exc = carry + s[threadIdx.x] - v;
    if (i < nb) bsum[i] = exc;
    int tile_total = s[255];
    __syncthreads();
    if (threadIdx.x == 0) carry += tile_total;
    __syncthreads();
  }
}

__global__ __launch_bounds__(256) void k_scan_finalG(int* __restrict__ a,
                                                     const int* __restrict__ bsum,
                                                     int M) {
  __shared__ int s[256];
  int i = blockIdx.x * 256 + threadIdx.x;
  int v = (i < M) ? a[i] : 0;
  s[threadIdx.x] = v;
  __syncthreads();
  for (int off = 1; off < 256; off <<= 1) {
    int t = (threadIdx.x >= off) ? s[threadIdx.x - off] : 0;
    __syncthreads();
    s[threadIdx.x] += t;
    __syncthreads();
  }
  if (i < M) a[i] = bsum[blockIdx.x] + s[threadIdx.x] - v;
}

// ---------------- pass B: bucket-grouped packed edges (int4 reads) ----------------

__global__ __launch_bounds__(256) void k_bucket(const int* __restrict__ row,
                                                const int* __restrict__ col,
                                                const int* __restrict__ counts,
                                                unsigned int* __restrict__ packed) {
  __shared__ int cur[NB];
  int g = blockIdx.x;
  for (int k = threadIdx.x; k < NB; k += 256) cur[k] = counts[k * GB + g];
  __syncthreads();
  int start = g * CHUNK;
  for (int gi = threadIdx.x; gi < CHUNK / 4; gi += 256) {
    int4 r4 = *reinterpret_cast<const int4*>(row + start + gi * 4);
    int4 c4 = *reinterpret_cast<const int4*>(col + start + gi * 4);
    int p0 = atomicAdd(&cur[r4.x >> 8], 1);
    int p1 = atomicAdd(&cur[r4.y >> 8], 1);
    int p2 = atomicAdd(&cur[r4.z >> 8], 1);
    int p3 = atomicAdd(&cur[r4.w >> 8], 1);
    packed[p0] = ((unsigned)(r4.x & 255) << 17) | (unsigned)c4.x;
    packed[p1] = ((unsigned)(r4.y & 255) << 17) | (unsigned)c4.y;
    packed[p2] = ((unsigned)(r4.z & 255) << 17) | (unsigned)c4.z;
    packed[p3] = ((unsigned)(r4.w & 255) << 17) | (unsigned)c4.w;
  }
}

// ---------------- pass C: per-bucket CSR finalize + fused x-cast ----------------

__global__ __launch_bounds__(256) void k_csr(const unsigned int* __restrict__ packed,
                                             const int* __restrict__ counts,
                                             int* __restrict__ rowptr,
                                             float* __restrict__ dis,
                                             int* __restrict__ csr_col,
                                             const float* __restrict__ x,
                                             unsigned short* __restrict__ xb,
                                             int N, int E) {
  __shared__ int rh[256];
  __shared__ int sc[256];
  __shared__ int cur[256];
  __shared__ float ldis[256];
  int b = blockIdx.x;
  int start = counts[b * GB];
  int end = (b + 1 < NB) ? counts[(b + 1) * GB] : E;

  rh[threadIdx.x] = 0;
  __syncthreads();
  for (int i = start + threadIdx.x; i < end; i += 256)
    atomicAdd(&rh[packed[i] >> 17], 1);
  __syncthreads();

  int v = rh[threadIdx.x];
  sc[threadIdx.x] = v;
  __syncthreads();
  for (int off = 1; off < 256; off <<= 1) {
    int t = (threadIdx.x >= off) ? sc[threadIdx.x - off] : 0;
    __syncthreads();
    sc[threadIdx.x] += t;
    __syncthreads();
  }
  int exc = sc[threadIdx.x] - v;

  float dv = 1.0f / sqrtf((float)v + 1e-12f);
  ldis[threadIdx.x] = dv;
  int gr = (b << 8) + threadIdx.x;
  if (gr < N) {
    rowptr[gr] = start + exc;
    dis[gr] = dv;
  }
  if (b == NB - 1 && threadIdx.x == 0) rowptr[N] = E;

  cur[threadIdx.x] = exc;
  __syncthreads();
  for (int i = start + threadIdx.x; i < end; i += 256) {
    unsigned p = packed[i];
    int lr = p >> 17;
    int c = (int)(p & 0x1FFFFu);
    int pos = atomicAdd(&cur[lr], 1);
    csr_col[start + pos] = c;
  }

  // fused cast: this bucket's rows of x -> bf16 * dis (coalesced float4 loop)
  int rows = min(256, N - (b << 8));
  if (rows > 0) {
    const float4* xs = reinterpret_cast<const float4*>(x + ((size_t)b << 8) * 32);
    ushort4* xd = reinterpret_cast<ushort4*>(xb + ((size_t)b << 8) * 32);
    for (int i = threadIdx.x; i < rows * 8; i += 256) {
      float ds = ldis[i >> 3];
      float4 vv = xs[i];
      xd[i] = make_ushort4(f2bf(vv.x * ds), f2bf(vv.y * ds),
                           f2bf(vv.z * ds), f2bf(vv.w * ds));
    }
  }
}

// ---------------- bf16 accumulate helper ----------------

template <int SQ>
static __device__ __forceinline__ void acc_bf(float* acc, const uint4* u) {
#pragma unroll
  for (int q = 0; q < SQ; ++q) {
    acc[8 * q + 0] += __uint_as_float(u[q].x << 16);
    acc[8 * q + 1] += __uint_as_float(u[q].x & 0xffff0000u);
    acc[8 * q + 2] += __uint_as_float(u[q].y << 16);
    acc[8 * q + 3] += __uint_as_float(u[q].y & 0xffff0000u);
    acc[8 * q + 4] += __uint_as_float(u[q].z << 16);
    acc[8 * q + 5] += __uint_as_float(u[q].z & 0xffff0000u);
    acc[8 * q + 6] += __uint_as_float(u[q].w << 16);
    acc[8 * q + 7] += __uint_as_float(u[q].w & 0xffff0000u);
  }
}

// ---------------- bf16 gather (4-deep): dst[r,:] = dis[r]*sum src[col,:] ----------------

template <int LPR, int SQ>
__global__ __launch_bounds__(256) void k_gather_bf(const uint4* __restrict__ src,
                                                   const int* __restrict__ rowptr,
                                                   const int* __restrict__ csr_col,
                                                   const float* __restrict__ dis,
                                                   float* __restrict__ dst, int N) {
  constexpr int RQ = LPR * SQ;
  constexpr int W = RQ * 8;
  int t = blockIdx.x * 256 + threadIdx.x;
  int r = t / LPR, g = t % LPR;
  if (r >= N) return;
  int j = rowptr[r], end = rowptr[r + 1];

  float acc[SQ * 8];
#pragma unroll
  for (int q = 0; q < SQ * 8; ++q) acc[q] = 0.f;

  for (; j + 4 <= end; j += 4) {
    int c0 = csr_col[j], c1 = csr_col[j + 1], c2 = csr_col[j + 2], c3 = csr_col[j + 3];
    const uint4* sp0 = src + (size_t)c0 * RQ + g * SQ;
    const uint4* sp1 = src + (size_t)c1 * RQ + g * SQ;
    const uint4* sp2 = src + (size_t)c2 * RQ + g * SQ;
    const uint4* sp3 = src + (size_t)c3 * RQ + g * SQ;
    uint4 u0[SQ], u1[SQ], u2[SQ], u3[SQ];
#pragma unroll
    for (int q = 0; q < SQ; ++q) u0[q] = sp0[q];
#pragma unroll
    for (int q = 0; q < SQ; ++q) u1[q] = sp1[q];
#pragma unroll
    for (int q = 0; q < SQ; ++q) u2[q] = sp2[q];
#pragma unroll
    for (int q = 0; q < SQ; ++q) u3[q] = sp3[q];
    acc_bf<SQ>(acc, u0);
    acc_bf<SQ>(acc, u1);
    acc_bf<SQ>(acc, u2);
    acc_bf<SQ>(acc, u3);
  }
  for (; j < end; ++j) {
    int c0 = csr_col[j];
    const uint4* sp0 = src + (size_t)c0 * RQ + g * SQ;
    uint4 u0[SQ];
#pragma unroll
    for (int q = 0; q < SQ; ++q) u0[q] = sp0[q];
    acc_bf<SQ>(acc, u0);
  }

  float ds = dis[r];
  float4* dp = reinterpret_cast<float4*>(dst + (size_t)r * W + g * (SQ * 8));
#pragma unroll
  for (int q = 0; q < SQ * 2; ++q)
    dp[q] = make_float4(ds * acc[4 * q + 0], ds * acc[4 * q + 1],
                        ds * acc[4 * q + 2], ds * acc[4 * q + 3]);
}

// ---------------- fused double GEMM, single row/thread, NO LDS ----------------
// s2 = bf16(dis*(relu(g1@W1)@W2)), rows padded to 64 bf16.
// Weights read DIRECTLY from global at compile-time-constant uniform offsets:
// compiler emits s_load_* (SMEM pipe) + SGPR-operand FMAs — frees the DS pipe
// that bounded the LDS-staged versions (R9: 960 ds_read_b128/thread, 41 µs).

__global__ __launch_bounds__(256) void k_gemm12(const float* __restrict__ g1,
                                                const float* __restrict__ W1,
                                                const float* __restrict__ W2,
                                                const float* __restrict__ dis,
                                                unsigned short* __restrict__ s2,
                                                int N) {
  int r = blockIdx.x * 256 + threadIdx.x;
  if (r >= N) return;

  float h[48];
#pragma unroll
  for (int f = 0; f < 48; ++f) h[f] = 0.f;

  const float4* xp = reinterpret_cast<const float4*>(g1 + (size_t)r * 32);
#pragma unroll
  for (int k4 = 0; k4 < 8; ++k4) {
    float4 v = xp[k4];
#pragma unroll
    for (int f = 0; f < 48; ++f) {
      h[f] = fmaf(v.x, W1[(4 * k4 + 0) * 48 + f], h[f]);
      h[f] = fmaf(v.y, W1[(4 * k4 + 1) * 48 + f], h[f]);
      h[f] = fmaf(v.z, W1[(4 * k4 + 2) * 48 + f], h[f]);
      h[f] = fmaf(v.w, W1[(4 * k4 + 3) * 48 + f], h[f]);
    }
  }
#pragma unroll
  for (int f = 0; f < 48; ++f) h[f] = fmaxf(h[f], 0.f);

  float ds = dis[r];
  uint4* op = reinterpret_cast<uint4*>(s2 + (size_t)r * 64);

#pragma unroll
  for (int fb = 0; fb < 3; ++fb) {  // 16 output features per block
    float o[16];
#pragma unroll
    for (int n = 0; n < 16; ++n) o[n] = 0.f;
#pragma unroll
    for (int k = 0; k < 48; ++k) {
      float hk = h[k];
#pragma unroll
      for (int n = 0; n < 16; ++n)
        o[n] = fmaf(hk, W2[k * 48 + fb * 16 + n], o[n]);
    }
    uint4 pk[2];
    unsigned* pw = reinterpret_cast<unsigned*>(pk);
#pragma unroll
    for (int i = 0; i < 8; ++i)
      pw[i] = (unsigned)f2bf(o[2 * i] * ds) |
              ((unsigned)f2bf(o[2 * i + 1] * ds) << 16);
    op[fb * 2] = pk[0];
    op[fb * 2 + 1] = pk[1];
  }
  uint4 z = make_uint4(0u, 0u, 0u, 0u);
  op[6] = z;
  op[7] = z;
}

// ---------------- fused layer-2 gather + layer-3 GEMM ----------------
// s3[r,:] = dis[r] * (relu(dis[r]*sum_j s2[col_j,:]) @ Wo)
// 8 lanes per row (padded 128B rows); shuffle-reduce over the 8-lane group.

__global__ __launch_bounds__(256) void k_gather_fc(const uint4* __restrict__ src,
                                                   const int* __restrict__ rowptr,
                                                   const int* __restrict__ csr_col,
                                                   const float* __restrict__ dis,
                                                   const float* __restrict__ Wo,
                                                   float* __restrict__ s3, int N) {
  __shared__ float Wol[64 * 8];
  for (int i = threadIdx.x; i < 512; i += 256) Wol[i] = (i < 384) ? Wo[i] : 0.f;
  __syncthreads();

  int t = blockIdx.x * 256 + threadIdx.x;
  int r = t >> 3, g = t & 7;
  if (r >= N) return;
  int j = rowptr[r], end = rowptr[r + 1];

  float acc[8];
#pragma unroll
  for (int q = 0; q < 8; ++q) acc[q] = 0.f;

  for (; j + 4 <= end; j += 4) {
    int c0 = csr_col[j], c1 = csr_col[j + 1], c2 = csr_col[j + 2], c3 = csr_col[j + 3];
    uint4 u0 = src[(size_t)c0 * 8 + g];
    uint4 u1 = src[(size_t)c1 * 8 + g];
    uint4 u2 = src[(size_t)c2 * 8 + g];
    uint4 u3 = src[(size_t)c3 * 8 + g];
    acc_bf<1>(acc, &u0);
    acc_bf<1>(acc, &u1);
    acc_bf<1>(acc, &u2);
    acc_bf<1>(acc, &u3);
  }
  for (; j < end; ++j) {
    uint4 u0 = src[(size_t)csr_col[j] * 8 + g];
    acc_bf<1>(acc, &u0);
  }

  float ds = dis[r];
  float v[8];
#pragma unroll
  for (int q = 0; q < 8; ++q) v[q] = fmaxf(ds * acc[q], 0.f);

  float p[8];
#pragma unroll
  for (int n = 0; n < 8; ++n) p[n] = 0.f;
  const int base = g * 8;
#pragma unroll
  for (int q = 0; q < 8; ++q) {
    float4 w0 = *reinterpret_cast<const float4*>(&Wol[(base + q) * 8]);
    float4 w1 = *reinterpret_cast<const float4*>(&Wol[(base + q) * 8 + 4]);
    p[0] = fmaf(v[q], w0.x, p[0]);
    p[1] = fmaf(v[q], w0.y, p[1]);
    p[2] = fmaf(v[q], w0.z, p[2]);
    p[3] = fmaf(v[q], w0.w, p[3]);
    p[4] = fmaf(v[q], w1.x, p[4]);
    p[5] = fmaf(v[q], w1.y, p[5]);
    p[6] = fmaf(v[q], w1.z, p[6]);
    p[7] = fmaf(v[q], w1.w, p[7]);
  }
#pragma unroll
  for (int m = 1; m < 8; m <<= 1) {
#pragma unroll
    for (int n = 0; n < 8; ++n) p[n] += __shfl_xor(p[n], m, 64);
  }
  if (g < 2) {
    float4 w = make_float4(ds * p[4 * g + 0], ds * p[4 * g + 1],
                           ds * p[4 * g + 2], ds * p[4 * g + 3]);
    *reinterpret_cast<float4*>(s3 + (size_t)r * 8 + 4 * g) = w;
  }
}

// ---------------- f32 gather (final 8-wide layer), 2-deep ----------------

template <int LPR, int FQ>
__global__ __launch_bounds__(256) void k_gather(const float* __restrict__ src,
                                                const int* __restrict__ rowptr,
                                                const int* __restrict__ csr_col,
                                                const float* __restrict__ dis,
                                                float* __restrict__ dst, int N) {
  constexpr int F = LPR * FQ * 4;
  int t = blockIdx.x * 256 + threadIdx.x;
  int r = t / LPR, g = t % LPR;
  if (r >= N) return;
  int j = rowptr[r], end = rowptr[r + 1];

  float acc[FQ * 4];
#pragma unroll
  for (int q = 0; q < FQ * 4; ++q) acc[q] = 0.f;

  for (; j + 2 <= end; j += 2) {
    int c0 = csr_col[j], c1 = csr_col[j + 1];
    const float4* sp0 =
        reinterpret_cast<const float4*>(src + (size_t)c0 * F + g * (FQ * 4));
    const float4* sp1 =
        reinterpret_cast<const float4*>(src + (size_t)c1 * F + g * (FQ * 4));
    float4 v0[FQ], v1[FQ];
#pragma unroll
    for (int q = 0; q < FQ; ++q) v0[q] = sp0[q];
#pragma unroll
    for (int q = 0; q < FQ; ++q) v1[q] = sp1[q];
#pragma unroll
    for (int q = 0; q < FQ; ++q) {
      acc[4 * q + 0] += v0[q].x + v1[q].x;
      acc[4 * q + 1] += v0[q].y + v1[q].y;
      acc[4 * q + 2] += v0[q].z + v1[q].z;
      acc[4 * q + 3] += v0[q].w + v1[q].w;
    }
  }
  if (j < end) {
    int c0 = csr_col[j];
    const float4* sp0 =
        reinterpret_cast<const float4*>(src + (size_t)c0 * F + g * (FQ * 4));
#pragma unroll
    for (int q = 0; q < FQ; ++q) {
      float4 v = sp0[q];
      acc[4 * q + 0] += v.x;
      acc[4 * q + 1] += v.y;
      acc[4 * q + 2] += v.z;
      acc[4 * q + 3] += v.w;
    }
  }

  float ds = dis[r];
  float4* dp = reinterpret_cast<float4*>(dst + (size_t)r * F + g * (FQ * 4));
#pragma unroll
  for (int q = 0; q < FQ; ++q)
    dp[q] = make_float4(ds * acc[4 * q + 0], ds * acc[4 * q + 1],
                        ds * acc[4 * q + 2], ds * acc[4 * q + 3]);
}

// ---------------- launch ----------------

extern "C" void kernel_launch(void* const* d_in, const int* in_sizes, int n_in,
                              void* d_out, int out_size, void* d_ws, size_t ws_size,
                              hipStream_t stream) {
  const float* x  = (const float*)d_in[0];
  const int*   ei = (const int*)d_in[1];
  const float* W1 = (const float*)d_in[2];
  const float* W2 = (const float*)d_in[3];
  const float* Wo = (const float*)d_in[4];
  float* out = (float*)d_out;

  const int N = NN, E = NE;
  const int* row = ei;
  const int* col = ei + E;
  const int scanG = (MCNT + 255) / 256;  // 382

  // workspace layout (word offsets; all 16B aligned)
  int*   counts  = (int*)d_ws;                   // 97752
  int*   bsum    = counts + 97752;               // 384
  int*   rowptr  = bsum + 384;                   // 100008
  float* dis     = (float*)(rowptr + 100008);    // 100000
  int*   csr_col = (int*)(dis + 100000);         // 1.6M
  float* A1      = (float*)(csr_col + NE);       // 3.2M words
  float* A2      = A1 + 3200000;                 // 4.0M words
  float* s3      = A2 + 4000000;                 // 800K words (N*8 f32)
  // aliases (lifetimes disjoint):
  unsigned int*   packed = (unsigned int*)A1;               // CSR build only
  unsigned short* s2     = (unsigned short*)A1;             // N*64 bf16 (padded)
  float*          g1     = A2;                              // N*32 f32
  unsigned short* xb     = (unsigned short*)(A2 + 3200000); // N*32 bf16

  // ---- CSR build (+fused cast) ----
  k_hist<<<GB, 256, 0, stream>>>(row, counts);
  k_bsumG<<<scanG, 256, 0, stream>>>(counts, bsum, MCNT);
  k_scan_bsum<<<1, 256, 0, stream>>>(bsum, scanG);
  k_scan_finalG<<<scanG, 256, 0, stream>>>(counts, bsum, MCNT);
  k_bucket<<<GB, 256, 0, stream>>>(row, col, counts, packed);
  k_csr<<<NB, 256, 0, stream>>>(packed, counts, rowptr, dis, csr_col, x, xb, N, E);

  // ---- layer 1 (reassociated): g1 = dis⊙(Ā@(dis⊙x)) ----
  k_gather_bf<4, 1><<<(N * 4 + 255) / 256, 256, 0, stream>>>(
      (const uint4*)xb, rowptr, csr_col, dis, g1, N);

  // ---- fused GEMM1+GEMM2 (scalar-load weights): s2 = bf16(dis*(relu(g1@W1)@W2)) ----
  k_gemm12<<<(N + 255) / 256, 256, 0, stream>>>(g1, W1, W2, dis, s2, N);

  // ---- fused layer-2 gather + layer-3 GEMM: s3 = dis*(relu(dis*(Ā@s2))@Wo) ----
  k_gather_fc<<<(N * 8 + 255) / 256, 256, 0, stream>>>(
      (const uint4*)s2, rowptr, csr_col, dis, Wo, s3, N);

  // ---- final gather: out = dis⊙(Ā@s3) ----
  k_gather<2, 1><<<(N * 2 + 255) / 256, 256, 0, stream>>>(s3, rowptr, csr_col,
                                                          dis, out, N);
}

// Round 12
// 141.485 us; speedup vs baseline: 8.4091x; 1.3065x over previous
//
#include <hip/hip_runtime.h>
#include <hip/hip_bf16.h>
#include <cstdint>
#include <cstddef>

static constexpr int NN = 100000;   // nodes
static constexpr int NE = 1600000;  // edges
static constexpr int NB = 391;      // buckets of 256 rows
static constexpr int GB = 250;      // blocks in hist/bucket passes (250*6400 == NE)
static constexpr int CHUNK = NE / GB;             // 6400 (int4-aligned chunks)
static constexpr int MCNT = NB * GB;              // 97750

typedef __attribute__((ext_vector_type(8))) short bf16x8;
typedef __attribute__((ext_vector_type(4))) float f32x4;

static __device__ __forceinline__ unsigned short f2bf(float f) {
  unsigned u = __float_as_uint(f);
  unsigned r = (u + 0x7fffu + ((u >> 16) & 1u)) >> 16;  // RNE
  return (unsigned short)r;
}

// ---------------- pass A: per-(bucket,block) histogram (int4 reads) ----------------

__global__ __launch_bounds__(256) void k_hist(const int* __restrict__ row,
                                              int* __restrict__ counts) {
  __shared__ int hist[NB];
  for (int k = threadIdx.x; k < NB; k += 256) hist[k] = 0;
  __syncthreads();
  int g = blockIdx.x;
  int start = g * CHUNK;
  for (int gi = threadIdx.x; gi < CHUNK / 4; gi += 256) {
    int4 r4 = *reinterpret_cast<const int4*>(row + start + gi * 4);
    atomicAdd(&hist[r4.x >> 8], 1);
    atomicAdd(&hist[r4.y >> 8], 1);
    atomicAdd(&hist[r4.z >> 8], 1);
    atomicAdd(&hist[r4.w >> 8], 1);
  }
  __syncthreads();
  for (int k = threadIdx.x; k < NB; k += 256) counts[k * GB + g] = hist[k];
}

// ---------------- generic 2-level exclusive scan ----------------

__global__ __launch_bounds__(256) void k_bsumG(const int* __restrict__ a,
                                               int* __restrict__ bsum, int M) {
  __shared__ int s[256];
  int i = blockIdx.x * 256 + threadIdx.x;
  s[threadIdx.x] = (i < M) ? a[i] : 0;
  __syncthreads();
  for (int off = 128; off > 0; off >>= 1) {
    if (threadIdx.x < off) s[threadIdx.x] += s[threadIdx.x + off];
    __syncthreads();
  }
  if (threadIdx.x == 0) bsum[blockIdx.x] = s[0];
}

__global__ __launch_bounds__(256) void k_scan_bsum(int* __restrict__ bsum, int nb) {
  __shared__ int s[256];
  __shared__ int carry;
  if (threadIdx.x == 0) carry = 0;
  __syncthreads();
  for (int base = 0; base < nb; base += 256) {
    int i = base + threadIdx.x;
    int v = (i < nb) ? bsum[i] : 0;
    s[threadIdx.x] = v;
    __syncthreads();
    for (int off = 1; off < 256; off <<= 1) {
      int t = (threadIdx.x >= off) ? s[threadIdx.x - off] : 0;
      __syncthreads();
      s[threadIdx.x] += t;
      __syncthreads();
    }
    int exc = carry + s[threadIdx.x] - v;
    if (i < nb) bsum[i] = exc;
    int tile_total = s[255];
    __syncthreads();
    if (threadIdx.x == 0) carry += tile_total;
    __syncthreads();
  }
}

__global__ __launch_bounds__(256) void k_scan_finalG(int* __restrict__ a,
                                                     const int* __restrict__ bsum,
                                                     int M) {
  __shared__ int s[256];
  int i = blockIdx.x * 256 + threadIdx.x;
  int v = (i < M) ? a[i] : 0;
  s[threadIdx.x] = v;
  __syncthreads();
  for (int off = 1; off < 256; off <<= 1) {
    int t = (threadIdx.x >= off) ? s[threadIdx.x - off] : 0;
    __syncthreads();
    s[threadIdx.x] += t;
    __syncthreads();
  }
  if (i < M) a[i] = bsum[blockIdx.x] + s[threadIdx.x] - v;
}

// ---------------- pass B: bucket-grouped packed edges (int4 reads) ----------------

__global__ __launch_bounds__(256) void k_bucket(const int* __restrict__ row,
                                                const int* __restrict__ col,
                                                const int* __restrict__ counts,
                                                unsigned int* __restrict__ packed) {
  __shared__ int cur[NB];
  int g = blockIdx.x;
  for (int k = threadIdx.x; k < NB; k += 256) cur[k] = counts[k * GB + g];
  __syncthreads();
  int start = g * CHUNK;
  for (int gi = threadIdx.x; gi < CHUNK / 4; gi += 256) {
    int4 r4 = *reinterpret_cast<const int4*>(row + start + gi * 4);
    int4 c4 = *reinterpret_cast<const int4*>(col + start + gi * 4);
    int p0 = atomicAdd(&cur[r4.x >> 8], 1);
    int p1 = atomicAdd(&cur[r4.y >> 8], 1);
    int p2 = atomicAdd(&cur[r4.z >> 8], 1);
    int p3 = atomicAdd(&cur[r4.w >> 8], 1);
    packed[p0] = ((unsigned)(r4.x & 255) << 17) | (unsigned)c4.x;
    packed[p1] = ((unsigned)(r4.y & 255) << 17) | (unsigned)c4.y;
    packed[p2] = ((unsigned)(r4.z & 255) << 17) | (unsigned)c4.z;
    packed[p3] = ((unsigned)(r4.w & 255) << 17) | (unsigned)c4.w;
  }
}

// ---------------- pass C: per-bucket CSR finalize + fused x-cast ----------------

__global__ __launch_bounds__(256) void k_csr(const unsigned int* __restrict__ packed,
                                             const int* __restrict__ counts,
                                             int* __restrict__ rowptr,
                                             float* __restrict__ dis,
                                             int* __restrict__ csr_col,
                                             const float* __restrict__ x,
                                             unsigned short* __restrict__ xb,
                                             int N, int E) {
  __shared__ int rh[256];
  __shared__ int sc[256];
  __shared__ int cur[256];
  __shared__ float ldis[256];
  int b = blockIdx.x;
  int start = counts[b * GB];
  int end = (b + 1 < NB) ? counts[(b + 1) * GB] : E;

  rh[threadIdx.x] = 0;
  __syncthreads();
  for (int i = start + threadIdx.x; i < end; i += 256)
    atomicAdd(&rh[packed[i] >> 17], 1);
  __syncthreads();

  int v = rh[threadIdx.x];
  sc[threadIdx.x] = v;
  __syncthreads();
  for (int off = 1; off < 256; off <<= 1) {
    int t = (threadIdx.x >= off) ? sc[threadIdx.x - off] : 0;
    __syncthreads();
    sc[threadIdx.x] += t;
    __syncthreads();
  }
  int exc = sc[threadIdx.x] - v;

  float dv = 1.0f / sqrtf((float)v + 1e-12f);
  ldis[threadIdx.x] = dv;
  int gr = (b << 8) + threadIdx.x;
  if (gr < N) {
    rowptr[gr] = start + exc;
    dis[gr] = dv;
  }
  if (b == NB - 1 && threadIdx.x == 0) rowptr[N] = E;

  cur[threadIdx.x] = exc;
  __syncthreads();
  for (int i = start + threadIdx.x; i < end; i += 256) {
    unsigned p = packed[i];
    int lr = p >> 17;
    int c = (int)(p & 0x1FFFFu);
    int pos = atomicAdd(&cur[lr], 1);
    csr_col[start + pos] = c;
  }

  // fused cast: this bucket's rows of x -> bf16 * dis (coalesced float4 loop)
  int rows = min(256, N - (b << 8));
  if (rows > 0) {
    const float4* xs = reinterpret_cast<const float4*>(x + ((size_t)b << 8) * 32);
    ushort4* xd = reinterpret_cast<ushort4*>(xb + ((size_t)b << 8) * 32);
    for (int i = threadIdx.x; i < rows * 8; i += 256) {
      float ds = ldis[i >> 3];
      float4 vv = xs[i];
      xd[i] = make_ushort4(f2bf(vv.x * ds), f2bf(vv.y * ds),
                           f2bf(vv.z * ds), f2bf(vv.w * ds));
    }
  }
}

// ---------------- bf16 accumulate helper ----------------

template <int SQ>
static __device__ __forceinline__ void acc_bf(float* acc, const uint4* u) {
#pragma unroll
  for (int q = 0; q < SQ; ++q) {
    acc[8 * q + 0] += __uint_as_float(u[q].x << 16);
    acc[8 * q + 1] += __uint_as_float(u[q].x & 0xffff0000u);
    acc[8 * q + 2] += __uint_as_float(u[q].y << 16);
    acc[8 * q + 3] += __uint_as_float(u[q].y & 0xffff0000u);
    acc[8 * q + 4] += __uint_as_float(u[q].z << 16);
    acc[8 * q + 5] += __uint_as_float(u[q].z & 0xffff0000u);
    acc[8 * q + 6] += __uint_as_float(u[q].w << 16);
    acc[8 * q + 7] += __uint_as_float(u[q].w & 0xffff0000u);
  }
}

// ---------------- layer-1 gather, bf16 OUTPUT: g1b[r,:] = bf16(dis[r]*sum src[col,:]) ----
// LPR=4 lanes/row, 8 feats/lane; 4-deep MLP unroll.

__global__ __launch_bounds__(256) void k_gather_bf1(const uint4* __restrict__ src,
                                                    const int* __restrict__ rowptr,
                                                    const int* __restrict__ csr_col,
                                                    const float* __restrict__ dis,
                                                    unsigned short* __restrict__ dst,
                                                    int N) {
  int t = blockIdx.x * 256 + threadIdx.x;
  int r = t >> 2, g = t & 3;
  if (r >= N) return;
  int j = rowptr[r], end = rowptr[r + 1];

  float acc[8];
#pragma unroll
  for (int q = 0; q < 8; ++q) acc[q] = 0.f;

  for (; j + 4 <= end; j += 4) {
    int c0 = csr_col[j], c1 = csr_col[j + 1], c2 = csr_col[j + 2], c3 = csr_col[j + 3];
    uint4 u0 = src[(size_t)c0 * 4 + g];
    uint4 u1 = src[(size_t)c1 * 4 + g];
    uint4 u2 = src[(size_t)c2 * 4 + g];
    uint4 u3 = src[(size_t)c3 * 4 + g];
    acc_bf<1>(acc, &u0);
    acc_bf<1>(acc, &u1);
    acc_bf<1>(acc, &u2);
    acc_bf<1>(acc, &u3);
  }
  for (; j < end; ++j) {
    uint4 u0 = src[(size_t)csr_col[j] * 4 + g];
    acc_bf<1>(acc, &u0);
  }

  float ds = dis[r];
  uint4 pk;
  unsigned* pw = reinterpret_cast<unsigned*>(&pk);
#pragma unroll
  for (int i = 0; i < 4; ++i)
    pw[i] = (unsigned)f2bf(ds * acc[2 * i]) |
            ((unsigned)f2bf(ds * acc[2 * i + 1]) << 16);
  *reinterpret_cast<uint4*>(dst + (size_t)r * 32 + g * 8) = pk;
}

// ---------------- MFMA fused double GEMM ----------------
// s2 = bf16(dis*(relu(g1b@W1)@W2)), rows padded to 64 bf16.
// Swapped operands: A = W^T tiles (weights live in 36 VGPRs of fragments),
// B = 16 node-rows. 9 MFMAs per wave; per-wave LDS tile (16x72, 2-way-free)
// re-fragments h between GEMMs and linearizes the epilogue stores.

__global__ __launch_bounds__(256) void k_gemm12_mfma(
    const unsigned short* __restrict__ g1b,   // [N][32] bf16
    const float* __restrict__ W1,             // [32][48]
    const float* __restrict__ W2,             // [48][48]
    const float* __restrict__ dis,
    unsigned short* __restrict__ s2,          // [N][64] bf16 (padded)
    int N) {
  __shared__ __align__(16) unsigned short hl[4][16][72];

  int w = threadIdx.x >> 6;   // wave id
  int l = threadIdx.x & 63;
  int c = l & 15;             // node-row slot within tile (MFMA col)
  int g = l >> 4;             // k-group
  int rb = blockIdx.x * 64 + w * 16;
  int r = rb + c;
  int rc = min(r, N - 1);

  // ---- weight fragments (one-time, L2-cached) ----
  // A-frag layout: lane holds A[m = l&15][k = (l>>4)*8 + i], i=0..7.
  bf16x8 w1f[3];
#pragma unroll
  for (int t = 0; t < 3; ++t) {
#pragma unroll
    for (int i = 0; i < 8; ++i)
      w1f[t][i] = (short)f2bf(W1[(g * 8 + i) * 48 + 16 * t + c]);  // W1^T[m=16t+c][k]
  }
  bf16x8 w2f[3][2];
#pragma unroll
  for (int t = 0; t < 3; ++t) {
#pragma unroll
    for (int s = 0; s < 2; ++s) {
#pragma unroll
      for (int i = 0; i < 8; ++i) {
        int k = s * 32 + g * 8 + i;
        w2f[t][s][i] = (k < 48) ? (short)f2bf(W2[k * 48 + 16 * t + c]) : (short)0;
      }
    }
  }

  // ---- GEMM1: h^T = W1^T @ g1^T  (3 MFMAs) ----
  bf16x8 bfr = *reinterpret_cast<const bf16x8*>(g1b + (size_t)rc * 32 + g * 8);
  f32x4 a1[3];
#pragma unroll
  for (int t = 0; t < 3; ++t) {
    a1[t] = f32x4{0.f, 0.f, 0.f, 0.f};
    a1[t] = __builtin_amdgcn_mfma_f32_16x16x32_bf16(w1f[t], bfr, a1[t], 0, 0, 0);
  }

  // relu -> bf16 -> LDS (lane holds node-row c, feats f = 16t+4g+j)
#pragma unroll
  for (int t = 0; t < 3; ++t) {
    int f = 16 * t + 4 * g;
    unsigned p0 = (unsigned)f2bf(fmaxf(a1[t][0], 0.f)) |
                  ((unsigned)f2bf(fmaxf(a1[t][1], 0.f)) << 16);
    unsigned p1 = (unsigned)f2bf(fmaxf(a1[t][2], 0.f)) |
                  ((unsigned)f2bf(fmaxf(a1[t][3], 0.f)) << 16);
    *reinterpret_cast<unsigned*>(&hl[w][c][f]) = p0;
    *reinterpret_cast<unsigned*>(&hl[w][c][f + 2]) = p1;
  }
  // zero-pad feats 48..63 (also pads the s2 row in the epilogue readback)
  *reinterpret_cast<unsigned*>(&hl[w][c][48 + 4 * g]) = 0u;
  *reinterpret_cast<unsigned*>(&hl[w][c][48 + 4 * g + 2]) = 0u;

  // ---- GEMM2: o^T = W2^T @ h^T  (2 K-steps x 3 tiles) ----
  f32x4 a2[3];
#pragma unroll
  for (int t = 0; t < 3; ++t) a2[t] = f32x4{0.f, 0.f, 0.f, 0.f};
#pragma unroll
  for (int s = 0; s < 2; ++s) {
    bf16x8 hb = *reinterpret_cast<const bf16x8*>(&hl[w][c][s * 32 + 8 * g]);
#pragma unroll
    for (int t = 0; t < 3; ++t)
      a2[t] = __builtin_amdgcn_mfma_f32_16x16x32_bf16(w2f[t][s], hb, a2[t], 0, 0, 0);
  }

  // ---- epilogue: *dis, ->bf16, LDS bounce, coalesced uint4 stores ----
  float ds = dis[rc];
#pragma unroll
  for (int t = 0; t < 3; ++t) {
    int f = 16 * t + 4 * g;
    unsigned p0 = (unsigned)f2bf(ds * a2[t][0]) |
                  ((unsigned)f2bf(ds * a2[t][1]) << 16);
    unsigned p1 = (unsigned)f2bf(ds * a2[t][2]) |
                  ((unsigned)f2bf(ds * a2[t][3]) << 16);
    *reinterpret_cast<unsigned*>(&hl[w][c][f]) = p0;
    *reinterpret_cast<unsigned*>(&hl[w][c][f + 2]) = p1;
  }
#pragma unroll
  for (int h2 = 0; h2 < 2; ++h2) {
    int q = l + 64 * h2;
    int rowq = q >> 3, off = q & 7;
    int rr = rb + rowq;
    if (rr < N) {
      uint4 v = *reinterpret_cast<const uint4*>(&hl[w][rowq][off * 8]);
      *reinterpret_cast<uint4*>(s2 + (size_t)rr * 64 + off * 8) = v;
    }
  }
}

// ---------------- fused layer-2 gather + layer-3 GEMM ----------------
// s3[r,:] = dis[r] * (relu(dis[r]*sum_j s2[col_j,:]) @ Wo)

__global__ __launch_bounds__(256) void k_gather_fc(const uint4* __restrict__ src,
                                                   const int* __restrict__ rowptr,
                                                   const int* __restrict__ csr_col,
                                                   const float* __restrict__ dis,
                                                   const float* __restrict__ Wo,
                                                   float* __restrict__ s3, int N) {
  __shared__ float Wol[64 * 8];
  for (int i = threadIdx.x; i < 512; i += 256) Wol[i] = (i < 384) ? Wo[i] : 0.f;
  __syncthreads();

  int t = blockIdx.x * 256 + threadIdx.x;
  int r = t >> 3, g = t & 7;
  if (r >= N) return;
  int j = rowptr[r], end = rowptr[r + 1];

  float acc[8];
#pragma unroll
  for (int q = 0; q < 8; ++q) acc[q] = 0.f;

  for (; j + 4 <= end; j += 4) {
    int c0 = csr_col[j], c1 = csr_col[j + 1], c2 = csr_col[j + 2], c3 = csr_col[j + 3];
    uint4 u0 = src[(size_t)c0 * 8 + g];
    uint4 u1 = src[(size_t)c1 * 8 + g];
    uint4 u2 = src[(size_t)c2 * 8 + g];
    uint4 u3 = src[(size_t)c3 * 8 + g];
    acc_bf<1>(acc, &u0);
    acc_bf<1>(acc, &u1);
    acc_bf<1>(acc, &u2);
    acc_bf<1>(acc, &u3);
  }
  for (; j < end; ++j) {
    uint4 u0 = src[(size_t)csr_col[j] * 8 + g];
    acc_bf<1>(acc, &u0);
  }

  float ds = dis[r];
  float v[8];
#pragma unroll
  for (int q = 0; q < 8; ++q) v[q] = fmaxf(ds * acc[q], 0.f);

  float p[8];
#pragma unroll
  for (int n = 0; n < 8; ++n) p[n] = 0.f;
  const int base = g * 8;
#pragma unroll
  for (int q = 0; q < 8; ++q) {
    float4 w0 = *reinterpret_cast<const float4*>(&Wol[(base + q) * 8]);
    float4 w1 = *reinterpret_cast<const float4*>(&Wol[(base + q) * 8 + 4]);
    p[0] = fmaf(v[q], w0.x, p[0]);
    p[1] = fmaf(v[q], w0.y, p[1]);
    p[2] = fmaf(v[q], w0.z, p[2]);
    p[3] = fmaf(v[q], w0.w, p[3]);
    p[4] = fmaf(v[q], w1.x, p[4]);
    p[5] = fmaf(v[q], w1.y, p[5]);
    p[6] = fmaf(v[q], w1.z, p[6]);
    p[7] = fmaf(v[q], w1.w, p[7]);
  }
#pragma unroll
  for (int m = 1; m < 8; m <<= 1) {
#pragma unroll
    for (int n = 0; n < 8; ++n) p[n] += __shfl_xor(p[n], m, 64);
  }
  if (g < 2) {
    float4 w = make_float4(ds * p[4 * g + 0], ds * p[4 * g + 1],
                           ds * p[4 * g + 2], ds * p[4 * g + 3]);
    *reinterpret_cast<float4*>(s3 + (size_t)r * 8 + 4 * g) = w;
  }
}

// ---------------- f32 gather (final 8-wide layer), 2-deep ----------------

template <int LPR, int FQ>
__global__ __launch_bounds__(256) void k_gather(const float* __restrict__ src,
                                                const int* __restrict__ rowptr,
                                                const int* __restrict__ csr_col,
                                                const float* __restrict__ dis,
                                                float* __restrict__ dst, int N) {
  constexpr int F = LPR * FQ * 4;
  int t = blockIdx.x * 256 + threadIdx.x;
  int r = t / LPR, g = t % LPR;
  if (r >= N) return;
  int j = rowptr[r], end = rowptr[r + 1];

  float acc[FQ * 4];
#pragma unroll
  for (int q = 0; q < FQ * 4; ++q) acc[q] = 0.f;

  for (; j + 2 <= end; j += 2) {
    int c0 = csr_col[j], c1 = csr_col[j + 1];
    const float4* sp0 =
        reinterpret_cast<const float4*>(src + (size_t)c0 * F + g * (FQ * 4));
    const float4* sp1 =
        reinterpret_cast<const float4*>(src + (size_t)c1 * F + g * (FQ * 4));
    float4 v0[FQ], v1[FQ];
#pragma unroll
    for (int q = 0; q < FQ; ++q) v0[q] = sp0[q];
#pragma unroll
    for (int q = 0; q < FQ; ++q) v1[q] = sp1[q];
#pragma unroll
    for (int q = 0; q < FQ; ++q) {
      acc[4 * q + 0] += v0[q].x + v1[q].x;
      acc[4 * q + 1] += v0[q].y + v1[q].y;
      acc[4 * q + 2] += v0[q].z + v1[q].z;
      acc[4 * q + 3] += v0[q].w + v1[q].w;
    }
  }
  if (j < end) {
    int c0 = csr_col[j];
    const float4* sp0 =
        reinterpret_cast<const float4*>(src + (size_t)c0 * F + g * (FQ * 4));
#pragma unroll
    for (int q = 0; q < FQ; ++q) {
      float4 v = sp0[q];
      acc[4 * q + 0] += v.x;
      acc[4 * q + 1] += v.y;
      acc[4 * q + 2] += v.z;
      acc[4 * q + 3] += v.w;
    }
  }

  float ds = dis[r];
  float4* dp = reinterpret_cast<float4*>(dst + (size_t)r * F + g * (FQ * 4));
#pragma unroll
  for (int q = 0; q < FQ; ++q)
    dp[q] = make_float4(ds * acc[4 * q + 0], ds * acc[4 * q + 1],
                        ds * acc[4 * q + 2], ds * acc[4 * q + 3]);
}

// ---------------- launch ----------------

extern "C" void kernel_launch(void* const* d_in, const int* in_sizes, int n_in,
                              void* d_out, int out_size, void* d_ws, size_t ws_size,
                              hipStream_t stream) {
  const float* x  = (const float*)d_in[0];
  const int*   ei = (const int*)d_in[1];
  const float* W1 = (const float*)d_in[2];
  const float* W2 = (const float*)d_in[3];
  const float* Wo = (const float*)d_in[4];
  float* out = (float*)d_out;

  const int N = NN, E = NE;
  const int* row = ei;
  const int* col = ei + E;
  const int scanG = (MCNT + 255) / 256;  // 382

  // workspace layout (word offsets; all 16B aligned)
  int*   counts  = (int*)d_ws;                   // 97752
  int*   bsum    = counts + 97752;               // 384
  int*   rowptr  = bsum + 384;                   // 100008
  float* dis     = (float*)(rowptr + 100008);    // 100000
  int*   csr_col = (int*)(dis + 100000);         // 1.6M
  float* A1      = (float*)(csr_col + NE);       // 3.2M words
  float* A2      = A1 + 3200000;                 // 4.0M words
  float* s3      = A2 + 4000000;                 // 800K words (N*8 f32)
  // aliases (lifetimes disjoint):
  unsigned int*   packed = (unsigned int*)A1;               // CSR build only
  unsigned short* s2     = (unsigned short*)A1;             // N*64 bf16 (padded)
  unsigned short* g1b    = (unsigned short*)A2;             // N*32 bf16
  unsigned short* xb     = (unsigned short*)(A2 + 3200000); // N*32 bf16

  // ---- CSR build (+fused cast) ----
  k_hist<<<GB, 256, 0, stream>>>(row, counts);
  k_bsumG<<<scanG, 256, 0, stream>>>(counts, bsum, MCNT);
  k_scan_bsum<<<1, 256, 0, stream>>>(bsum, scanG);
  k_scan_finalG<<<scanG, 256, 0, stream>>>(counts, bsum, MCNT);
  k_bucket<<<GB, 256, 0, stream>>>(row, col, counts, packed);
  k_csr<<<NB, 256, 0, stream>>>(packed, counts, rowptr, dis, csr_col, x, xb, N, E);

  // ---- layer 1 (reassociated): g1b = bf16(dis⊙(Ā@(dis⊙x))) ----
  k_gather_bf1<<<(N * 4 + 255) / 256, 256, 0, stream>>>(
      (const uint4*)xb, rowptr, csr_col, dis, g1b, N);

  // ---- MFMA fused GEMM1+GEMM2: s2 = bf16(dis*(relu(g1b@W1)@W2)), padded 64 ----
  k_gemm12_mfma<<<(N + 63) / 64, 256, 0, stream>>>(g1b, W1, W2, dis, s2, N);

  // ---- fused layer-2 gather + layer-3 GEMM: s3 = dis*(relu(dis*(Ā@s2))@Wo) ----
  k_gather_fc<<<(N * 8 + 255) / 256, 256, 0, stream>>>(
      (const uint4*)s2, rowptr, csr_col, dis, Wo, s3, N);

  // ---- final gather: out = dis⊙(Ā@s3) ----
  k_gather<2, 1><<<(N * 2 + 255) / 256, 256, 0, stream>>>(s3, rowptr, csr_col,
                                                          dis, out, N);
}